// Round 1
// baseline (1998.684 us; speedup 1.0000x reference)
//
#include <hip/hip_runtime.h>
#include <hip/hip_bf16.h>

typedef unsigned short u16;
typedef unsigned int   u32;
typedef __attribute__((ext_vector_type(8))) __bf16 bf16x8;
typedef __attribute__((ext_vector_type(4))) float  f32x4;
typedef __attribute__((ext_vector_type(4))) u16    u16x4;

#define NN   1024
#define TT   64
#define LL   62
#define CIN  32
#define COUT 32

__device__ __forceinline__ u16 f2bf(float f){
  u32 u = __builtin_bit_cast(u32, f);
  return (u16)((u + 0x7fffu + ((u >> 16) & 1u)) >> 16);   // RNE
}
__device__ __forceinline__ bf16x8 ld8(const u16* p){ return *(const bf16x8*)p; }

#define MFMA16(a,b,c) __builtin_amdgcn_mfma_f32_16x16x32_bf16((a),(b),(c),0,0,0)
#define GLL16(g,l) __builtin_amdgcn_global_load_lds((const __attribute__((address_space(1))) void*)(g), (__attribute__((address_space(3))) void*)(l), 16, 0, 0)

// ---------- supports -> bf16 ----------
__global__ __launch_bounds__(256) void k_cvt_supports(const float* __restrict__ s0, const float* __restrict__ s1,
                                                      const float* __restrict__ s2, const float* __restrict__ s3,
                                                      u16* __restrict__ Sb){
  const float* srcs[4] = {s0, s1, s2, s3};
  const float* sp = srcs[blockIdx.y];
  u32 i = blockIdx.x * 256u + threadIdx.x;
  Sb[(size_t)blockIdx.y * (size_t)(NN*NN) + i] = f2bf(sp[i]);
}

// ---------- fold weights, BN constants ----------
__global__ __launch_bounds__(256) void k_prep_weights(const float* __restrict__ Wg, const float* __restrict__ Wm,
    const float* __restrict__ W1, const float* __restrict__ gamma, const float* __restrict__ beta,
    const float* __restrict__ rmean, const float* __restrict__ rvar,
    u16* __restrict__ WgB, u16* __restrict__ WmB, u16* __restrict__ W1B,
    float* __restrict__ scl, float* __restrict__ sft){
  int tid = threadIdx.x;
  // Wg_eff: k<32 -> Wg[:,3c]-Wg[:,3c+2] (xt, identity Cheby term + folded -X of L2)
  //         32..63 -> Wg[:,3c+1] (P_S), 64..95 -> 2*Wg[:,3c+2] (Q_S)
  for (int i = tid; i < 64*96; i += 256){
    int o = i / 96, k = i - o*96;
    float v;
    if (k < 32)      v = Wg[o*96 + 3*k] - Wg[o*96 + 3*k + 2];
    else if (k < 64) v = Wg[o*96 + 3*(k-32) + 1];
    else             v = 2.0f * Wg[o*96 + 3*(k-64) + 2];
    WgB[i] = f2bf(v);
  }
  for (int i = tid; i < 64*224; i += 256) WmB[i] = f2bf(Wm[i]);
  for (int i = tid; i < 64*32;  i += 256) W1B[i] = f2bf(W1[i]);
  if (tid < 64){
    float inv = gamma[tid] * rsqrtf(rvar[tid] + 1e-5f);
    scl[tid] = inv;
    sft[tid] = beta[tid] - rmean[tid]*inv;
  }
}

// ---------- time conv (VALID, Kt=3): xt_nat[bl][o][n][l] bf16 ----------
__global__ __launch_bounds__(256) void k_timeconv(const float* __restrict__ x, const float* __restrict__ Wt,
                                                  const float* __restrict__ bt, u16* __restrict__ xtN, int b0){
  __shared__ float xl[CIN][TT];        // 8 KB
  __shared__ float wl[COUT*CIN*3];     // 12 KB
  const int n = blockIdx.x, bl = blockIdx.y, b = b0 + bl;
  const int tid = threadIdx.x;
  for (int i = tid; i < CIN*TT; i += 256){
    int ci = i >> 6, t = i & 63;
    xl[ci][t] = x[((size_t)(b*CIN + ci)*NN + n)*TT + t];
  }
  for (int i = tid; i < COUT*CIN*3; i += 256) wl[i] = Wt[i];
  __syncthreads();
  const int l = tid & 63, og = tid >> 6;   // wave og handles o = og*8..og*8+7 (broadcast weights)
  if (l < LL){
    for (int oo = 0; oo < 8; ++oo){
      int o = og*8 + oo;
      float acc = bt[o];
      const float* w = &wl[(o*CIN)*3];
      #pragma unroll 4
      for (int ci = 0; ci < CIN; ++ci){
        acc += xl[ci][l]*w[0] + xl[ci][l+1]*w[1] + xl[ci][l+2]*w[2];
        w += 3;
      }
      xtN[((size_t)(bl*COUT + o)*NN + n)*LL + l] = f2bf(acc);
    }
  }
}

// ---------- transpose xt_nat -> Xp[m=(bl*62+l)*32+c][n] ----------
__global__ __launch_bounds__(256) void k_transpose(const u16* __restrict__ xtN, u16* __restrict__ Xp){
  __shared__ u16 tile[64][66];
  const int nt = blockIdx.x, c = blockIdx.y, bl = blockIdx.z;
  const int n0 = nt * 64;
  const int tid = threadIdx.x;
  const u16* src = xtN + ((size_t)(bl*COUT + c)*NN + n0)*LL;
  for (int i = tid; i < 64*31; i += 256){        // 64 rows x 31 dwords
    int r = i / 31, d = i - r*31;
    u32 v = *(const u32*)(src + (size_t)r*LL + 2*d);
    *(u32*)&tile[r][2*d] = v;
  }
  __syncthreads();
  for (int i = tid; i < LL*32; i += 256){        // 62 l x 32 dword-pairs of n
    int l = i >> 5, np = i & 31;
    u32 v = (u32)tile[2*np][l] | ((u32)tile[2*np+1][l] << 16);
    *(u32*)(Xp + ((size_t)((bl*LL + l)*32 + c))*NN + n0 + 2*np) = v;
  }
}

// ---------- graph GEMM: C[m][w] = sum_v A[m][v] * S_j[w][v]  (128x128 tile, BK=32) ----------
template<bool WRITE_PM>
__global__ __launch_bounds__(256) void k_gemm(const u16* __restrict__ Abase, const u16* __restrict__ Sb,
                                              u16* __restrict__ pm, u16* __restrict__ nm,
                                              int Mc, int Astride){
  __shared__ u16 Alds[128*32];
  __shared__ u16 Blds[128*32];
  const int j = blockIdx.z;
  const u16* A  = Abase + (size_t)j * (size_t)Astride;
  const u16* Bm = Sb + (size_t)j * (size_t)(NN*NN);
  const int m0 = blockIdx.x * 128, w0 = blockIdx.y * 128;
  const int tid = threadIdx.x, wid = tid >> 6;
  const int lane = tid & 63, fc = lane & 15, fh = lane >> 4;
  const int srow = tid >> 2, sch = tid & 3;
  const u16* gA0 = A  + (size_t)(m0 + srow)      * NN + sch*8;
  const u16* gA1 = A  + (size_t)(m0 + srow + 64) * NN + sch*8;
  const u16* gB0 = Bm + (size_t)(w0 + srow)      * NN + sch*8;
  const u16* gB1 = Bm + (size_t)(w0 + srow + 64) * NN + sch*8;
  u16* lA0 = Alds + wid*512;        u16* lA1 = Alds + 2048 + wid*512;
  u16* lB0 = Blds + wid*512;        u16* lB1 = Blds + 2048 + wid*512;
  const int wm = wid >> 1, wn = wid & 1;
  f32x4 acc[4][4] = {};
  for (int v0 = 0; v0 < NN; v0 += 32){
    GLL16(gA0 + v0, lA0);
    GLL16(gA1 + v0, lA1);
    GLL16(gB0 + v0, lB0);
    GLL16(gB1 + v0, lB1);
    __syncthreads();
    bf16x8 af[4], bf_[4];
    #pragma unroll
    for (int i = 0; i < 4; ++i){
      af[i]  = ld8(&Alds[(wm*64 + i*16 + fc)*32 + fh*8]);
      bf_[i] = ld8(&Blds[(wn*64 + i*16 + fc)*32 + fh*8]);
    }
    #pragma unroll
    for (int i = 0; i < 4; ++i)
      #pragma unroll
      for (int q = 0; q < 4; ++q)
        acc[i][q] = MFMA16(af[i], bf_[q], acc[i][q]);
    __syncthreads();
  }
  if (WRITE_PM){
    u16* pmj = pm + (size_t)j * (size_t)Mc * NN;
    #pragma unroll
    for (int i = 0; i < 4; ++i){
      int mb = m0 + wm*64 + i*16 + 4*fh;
      #pragma unroll
      for (int q = 0; q < 4; ++q){
        int wc = w0 + wn*64 + q*16 + fc;
        #pragma unroll
        for (int r = 0; r < 4; ++r)
          pmj[(size_t)(mb + r)*NN + wc] = f2bf(acc[i][q][r]);
      }
    }
  }
  {
    u16* nmj = nm + (size_t)j * (size_t)Mc * NN;
    #pragma unroll
    for (int i = 0; i < 4; ++i){
      int mb = m0 + wm*64 + i*16 + 4*fh;
      #pragma unroll
      for (int q = 0; q < 4; ++q){
        int wc = w0 + wn*64 + q*16 + fc;
        u16x4 pk = { f2bf(acc[i][q][0]), f2bf(acc[i][q][1]), f2bf(acc[i][q][2]), f2bf(acc[i][q][3]) };
        *(u16x4*)&nmj[(size_t)wc*Mc + mb] = pk;   // 4 consecutive m per lane
      }
    }
  }
}

// ---------- final: channel-mix MFMA + GLU + residual + BN ----------
__global__ __launch_bounds__(256) void k_final(
    const u16* __restrict__ xtN, const float* __restrict__ x,
    const u16* __restrict__ Pnm, const u16* __restrict__ Qnm,
    const u16* __restrict__ WgB, const u16* __restrict__ WmB, const u16* __restrict__ W1B,
    const float* __restrict__ bg, const float* __restrict__ bm, const float* __restrict__ b1,
    const float* __restrict__ scl, const float* __restrict__ sft,
    float* __restrict__ out, int b0, int Mc){
  __shared__ u16 V[64][328];   // rows l (62 valid), cols k: [X|P_S|Q_S|P0|Q0|P1|Q1|P2|Q2|xres]
  const int n = blockIdx.x, bl = blockIdx.y, b = b0 + bl;
  const int tid = threadIdx.x;
  // branches 1..8 from node-major GEMM outputs: slab = [l=62][c=32] contiguous
  for (int g = 1; g <= 8; ++g){
    int j = (g-1) >> 1;
    const u16* src = ((g & 1) ? Pnm : Qnm) + (size_t)j*(size_t)NN*Mc + (size_t)n*Mc + bl*1984;
    for (int i = tid; i < 992; i += 256){
      int l = i >> 4, cp = i & 15;
      u32 v = *(const u32*)(src + l*32 + 2*cp);
      *(u32*)&V[l][g*32 + 2*cp] = v;
    }
  }
  // branch 0: xt (from natural layout)
  for (int i = tid; i < CIN*LL; i += 256){
    int c = i / LL, l = i - c*LL;
    V[l][c] = xtN[((size_t)(bl*COUT + c)*NN + n)*LL + l];
  }
  // branch 9: residual source x[b][c][n][l+2]
  for (int i = tid; i < CIN*LL; i += 256){
    int c = i / LL, l = i - c*LL;
    V[l][288 + c] = f2bf(x[((size_t)(b*CIN + c)*NN + n)*TT + 2 + l]);
  }
  __syncthreads();

  const int wid = tid >> 6, lane = tid & 63, fc = lane & 15, fh = lane >> 4;
  const int lcol = wid*16 + fc;      // this lane's B-frag / D column = l
  f32x4 acc[12];
  #pragma unroll
  for (int i = 0; i < 12; ++i) acc[i] = (f32x4){0.f, 0.f, 0.f, 0.f};
  const u16* vrow = &V[lcol][0];

  #pragma unroll
  for (int s = 0; s < 3; ++s){                 // u1: K over {X, P_S, Q_S}
    bf16x8 bv = ld8(vrow + s*32 + 8*fh);
    #pragma unroll
    for (int t = 0; t < 4; ++t)
      acc[t] = MFMA16(ld8(WgB + (t*16 + fc)*96 + s*32 + 8*fh), bv, acc[t]);
  }
  const int ktab[7] = {0, 96, 128, 160, 192, 224, 256};
  #pragma unroll
  for (int s = 0; s < 7; ++s){                 // u2: K over {X, P0,Q0,P1,Q1,P2,Q2}
    bf16x8 bv = ld8(vrow + ktab[s] + 8*fh);
    #pragma unroll
    for (int t = 0; t < 4; ++t)
      acc[4+t] = MFMA16(ld8(WmB + (t*16 + fc)*224 + s*32 + 8*fh), bv, acc[4+t]);
  }
  {                                            // r: K over {xres}
    bf16x8 bv = ld8(vrow + 288 + 8*fh);
    #pragma unroll
    for (int t = 0; t < 4; ++t)
      acc[8+t] = MFMA16(ld8(W1B + (t*16 + fc)*32 + 8*fh), bv, acc[8+t]);
  }

  if (lcol < LL){
    float* ob = out + ((size_t)b*64*NN + n)*LL + lcol;
    #pragma unroll
    for (int t = 0; t < 2; ++t){
      #pragma unroll
      for (int r = 0; r < 4; ++r){
        int os = t*16 + 4*fh + r;              // 0..31
        float u1a = acc[t][r]   + bg[os];
        float u1b = acc[t+2][r] + bg[os+32];
        float s1  = fmaxf(u1a, 0.f) / (1.f + __expf(-u1b));
        float z1  = s1 + acc[8+t][r] + b1[os];
        ob[(size_t)os*(NN*LL)] = z1*scl[os] + sft[os];
        int o2 = 32 + os;
        float u2a = acc[4+t][r] + bm[os];
        float u2b = acc[6+t][r] + bm[os+32];
        float s2  = fmaxf(u2a, 0.f) / (1.f + __expf(-u2b));
        float z2  = s2 + acc[10+t][r] + b1[o2];
        ob[(size_t)o2*(NN*LL)] = z2*scl[o2] + sft[o2];
      }
    }
  }
}

extern "C" void kernel_launch(void* const* d_in, const int* in_sizes, int n_in,
                              void* d_out, int out_size, void* d_ws, size_t ws_size,
                              hipStream_t stream){
  const float* x    = (const float*)d_in[0];
  const float* sup  = (const float*)d_in[1];
  const float* sup0 = (const float*)d_in[2];
  const float* sup1 = (const float*)d_in[3];
  const float* sup2 = (const float*)d_in[4];
  const float* W1   = (const float*)d_in[5];
  const float* b1   = (const float*)d_in[6];
  const float* Wt   = (const float*)d_in[7];
  const float* bt   = (const float*)d_in[8];
  const float* Wg   = (const float*)d_in[9];
  const float* bg   = (const float*)d_in[10];
  const float* Wm   = (const float*)d_in[11];
  const float* bm   = (const float*)d_in[12];
  const float* gam  = (const float*)d_in[13];
  const float* bet  = (const float*)d_in[14];
  const float* rme  = (const float*)d_in[15];
  const float* rva  = (const float*)d_in[16];
  float* out = (float*)d_out;

  char* p = (char*)d_ws;
  auto carve = [&](size_t bytes)->char*{
    char* r = p; p += (bytes + 255) & ~(size_t)255; return r;
  };
  u16*   Sb  = (u16*)carve((size_t)4*NN*NN*2);
  u16*   WgB = (u16*)carve(64*96*2);
  u16*   WmB = (u16*)carve(64*224*2);
  u16*   W1B = (u16*)carve(64*32*2);
  float* scl = (float*)carve(64*4);
  float* sft = (float*)carve(64*4);
  size_t used = (size_t)(p - (char*)d_ws);

  const size_t unit = 4063232ull;             // bytes per batch per big buffer (32*1024*62*2)
  int CB = 16;
  while (CB > 2 && used + 14ull*CB*unit + 16*256 > ws_size) CB >>= 1;
  size_t bufB = (size_t)CB * unit;
  u16* xtN = (u16*)carve(bufB);
  u16* Xp  = (u16*)carve(bufB);
  u16* Ppm = (u16*)carve(4*bufB);
  u16* Pnm = (u16*)carve(4*bufB);
  u16* Qnm = (u16*)carve(4*bufB);
  int Mc = CB * 1984;

  k_cvt_supports<<<dim3(4096, 4), 256, 0, stream>>>(sup, sup0, sup1, sup2, Sb);
  k_prep_weights<<<1, 256, 0, stream>>>(Wg, Wm, W1, gam, bet, rme, rva, WgB, WmB, W1B, scl, sft);

  for (int b0 = 0; b0 < 16; b0 += CB){
    k_timeconv <<<dim3(1024, CB), 256, 0, stream>>>(x, Wt, bt, xtN, b0);
    k_transpose<<<dim3(16, 32, CB), 256, 0, stream>>>(xtN, Xp);
    k_gemm<true ><<<dim3(Mc/128, 8, 4), 256, 0, stream>>>(Xp,  Sb, Ppm, Pnm, Mc, 0);
    k_gemm<false><<<dim3(Mc/128, 8, 4), 256, 0, stream>>>(Ppm, Sb, (u16*)nullptr, Qnm, Mc, Mc*NN);
    k_final    <<<dim3(1024, CB), 256, 0, stream>>>(xtN, x, Pnm, Qnm, WgB, WmB, W1B,
                                                    bg, bm, b1, scl, sft, out, b0, Mc);
  }
}